// Round 15
// baseline (160.675 us; speedup 1.0000x reference)
//
#include <hip/hip_runtime.h>
#include <hip/hip_fp16.h>
#include <cstdio>
#include <cstdint>

#define NREL 16
#define NBASE 8
#define NPB 512            // nodes per super-bin (bin = dst >> 9)
#define NPLACE 256         // histogram/place blocks
// Record packing: src[16:0] | et[20:17] | dlow[29:21]  (N <= 2^17)

typedef _Float16 half8 __attribute__((ext_vector_type(8)));
typedef float floatx4 __attribute__((ext_vector_type(4)));

// ---------------------------------------------------------------------------
template <int CTRL>
__device__ __forceinline__ float dpp_add_f(float x) {
    int xi = __builtin_bit_cast(int, x);
    int yi = __builtin_amdgcn_update_dpp(0, xi, CTRL, 0xF, 0xF, true);
    return x + __builtin_bit_cast(float, yi);
}

// ---------------------------------------------------------------------------
// k_fused1: two independent jobs, selected by block range:
//   [0, nb_pre)          node_pre via MFMA (64 nodes/block, 16/wave):
//                        hA1 (fp16), hA2 (f32), curr (f32), h16 (A-frag cvt)
//   [nb_pre, +NPLACE)    hist2: per-(block,super-bin) LDS histogram of dst
// ---------------------------------------------------------------------------
__global__ __launch_bounds__(256) void k_fused1(
        const float* __restrict__ h, const float* __restrict__ A_w,
        const float* __restrict__ slw,
        const int* __restrict__ dst,
        __half* __restrict__ hA1, _Float16* __restrict__ h16,
        float* __restrict__ hA2, float* __restrict__ curr,
        int* __restrict__ histT,
        int N, int E, int nb_pre) {
    __shared__ int hist[256];
    int bx = blockIdx.x;
    int t = threadIdx.x;
    if (bx < nb_pre) {
        // ---- node_pre via MFMA ----
        int w = t >> 6, l = t & 63;
        int n0 = bx * 64 + w * 16;
        if (n0 >= N) return;
        int lr = l & 15, lg = l >> 4;
        int anode = n0 + lr;
        int arc = (anode < N) ? anode : N - 1;   // clamp; stores masked
        int ac = lg * 8;
        float4 hv0 = *(const float4*)&h[(size_t)arc * 32 + ac];
        float4 hv1 = *(const float4*)&h[(size_t)arc * 32 + ac + 4];
        half8 af;
        af[0] = (_Float16)hv0.x; af[1] = (_Float16)hv0.y;
        af[2] = (_Float16)hv0.z; af[3] = (_Float16)hv0.w;
        af[4] = (_Float16)hv1.x; af[5] = (_Float16)hv1.y;
        af[6] = (_Float16)hv1.z; af[7] = (_Float16)hv1.w;
        if (anode < N)
            *(uint4*)&h16[(size_t)anode * 32 + ac] = *(const uint4*)&af;
        #pragma unroll
        for (int g = 0; g < 6; ++g) {
            half8 bf;
            #pragma unroll
            for (int j = 0; j < 8; ++j) {
                int i = lg * 8 + j;                  // k index (h feature)
                int oc = g * 16 + lr;                // out col 0..95
                float v;
                if (g < 2)      v = A_w[i * 32 + oc];
                else if (g < 4) v = A_w[(32 + i) * 32 + (oc - 32)];
                else            v = slw[i * 32 + (oc - 64)];
                bf[j] = (_Float16)v;
            }
            floatx4 d = {0.f, 0.f, 0.f, 0.f};
            d = __builtin_amdgcn_mfma_f32_16x16x32_f16(af, bf, d, 0, 0, 0);
            #pragma unroll
            for (int q = 0; q < 4; ++q) {
                int node = n0 + lg * 4 + q;          // D row = node
                int oc = g * 16 + lr;                // D col = out col
                if (node < N) {
                    if (g < 2)      hA1[(size_t)node * 32 + oc] = __float2half(d[q]);
                    else if (g < 4) hA2[(size_t)node * 32 + (oc - 32)] = d[q];
                    else            curr[(size_t)node * 32 + (oc - 64)] = d[q];
                }
            }
        }
    } else {
        // ---- hist2 ----
        int nsb = (N + NPB - 1) / NPB;
        hist[t] = 0;
        __syncthreads();
        int blk = bx - nb_pre;
        int bpb = (E + NPLACE - 1) / NPLACE;
        int e0 = blk * bpb;
        int e1 = e0 + bpb; if (e1 > E) e1 = E;
        for (int e = e0 + t; e < e1; e += 256)
            atomicAdd(&hist[dst[e] >> 9], 1);
        __syncthreads();
        if (t < nsb) histT[t * NPLACE + blk] = hist[t];
    }
}

// ---------------------------------------------------------------------------
// k_scanH_prep: two jobs by block range:
//   [0, nsb)      per-super-bin exclusive scan of NPLACE block-counts
//                 (in place, bin-LOCAL); bin RAW total -> binTot[bin].
//   [nsb, +64)    prep: relwB16 (MFMA B-frag layout) + relA.
// ---------------------------------------------------------------------------
__global__ __launch_bounds__(NPLACE) void k_scanH_prep(
        int* __restrict__ histT, int* __restrict__ binTot,
        const float* __restrict__ weight, const float* __restrict__ w_comp,
        const float* __restrict__ attn_emb, const float* __restrict__ A_w,
        const float* __restrict__ A_b,
        _Float16* __restrict__ relwB16, float* __restrict__ relA, int nsb) {
    __shared__ int sd[NPLACE];
    int bx = blockIdx.x, t = threadIdx.x;
    if (bx < nsb) {
        int bin = bx;
        int v = histT[bin * NPLACE + t];
        sd[t] = v;
        __syncthreads();
        for (int off = 1; off < NPLACE; off <<= 1) {
            int x = (t >= off) ? sd[t - off] : 0;
            __syncthreads();
            sd[t] += x;
            __syncthreads();
        }
        histT[bin * NPLACE + t] = sd[t] - v;
        if (t == NPLACE - 1) binTot[bin] = sd[NPLACE - 1];
    } else {
        int pidx = (bx - nsb) * 256 + t;             // 0..16383
        int r = pidx >> 10, rem = pidx & 1023;
        int nb = rem >> 9, lj = rem & 511;
        int l = lj >> 3, j = lj & 7;
        int i = ((l >> 4) << 3) + j;                 // k index
        int o = nb * 16 + (l & 15);                  // n index
        float acc = 0.f;
        #pragma unroll
        for (int b = 0; b < NBASE; ++b)
            acc += w_comp[r * NBASE + b] * weight[b * 1024 + i * 32 + o];
        relwB16[pidx] = (_Float16)acc;
        if (pidx < 512) {
            int rr = pidx >> 5, oo = pidx & 31;
            float a = A_b[oo];
            #pragma unroll 8
            for (int ii = 0; ii < 32; ++ii)
                a += attn_emb[rr * 32 + ii] * A_w[(64 + ii) * 32 + oo];
            relA[pidx] = a;
        }
    }
}

// ---------------------------------------------------------------------------
// k_fused2: two independent jobs by block range:
//   [0, nb_hrel)          hrel via MFMA: 16-node tile, wave w covers
//                         col-groups w*8..w*8+7; D staged in LDS, written
//                         coalesced as uint4.
//   [nb_hrel, +NPLACE)    place: local scan of raw binTot -> absolute bases;
//                         LDS cursors, contiguous runs, LDS atomics only.
// ---------------------------------------------------------------------------
__global__ __launch_bounds__(256) void k_fused2(
        const _Float16* __restrict__ h16, const _Float16* __restrict__ relwB16,
        __half* __restrict__ hrel16,
        const int* __restrict__ src, const int* __restrict__ dst,
        const int* __restrict__ et,
        const int* __restrict__ histT, const int* __restrict__ binTot,
        int* __restrict__ tmp,
        int N, int E, int nb_hrel) {
    __shared__ __align__(16) _Float16 tile[16 * 512];   // 16KB
    __shared__ int cur[256];
    __shared__ int sd[256];
    int bx = blockIdx.x;
    int t = threadIdx.x;
    if (bx < nb_hrel) {
        int n0 = bx * 16;
        int l = t & 63, w = t >> 6;
        int ar = n0 + (l & 15);
        if (ar >= N) ar = N - 1;
        half8 af = *(const half8*)(h16 + (size_t)ar * 32 + ((l >> 4) << 3));
        #pragma unroll
        for (int gg = 0; gg < 8; ++gg) {
            int g = w * 8 + gg;
            half8 bf = *(const half8*)(relwB16 + (size_t)g * 512 + l * 8);
            floatx4 d = {0.f, 0.f, 0.f, 0.f};
            d = __builtin_amdgcn_mfma_f32_16x16x32_f16(af, bf, d, 0, 0, 0);
            #pragma unroll
            for (int q = 0; q < 4; ++q) {
                int row = ((l >> 4) << 2) + q;
                tile[row * 512 + g * 16 + (l & 15)] = (_Float16)d[q];
            }
        }
        __syncthreads();
        #pragma unroll
        for (int p = 0; p < 4; ++p) {
            int idx = p * 256 + t;
            int row = idx >> 6, c8 = (idx & 63) << 3;
            int n = n0 + row;
            if (n < N)
                *(uint4*)&hrel16[(size_t)n * 512 + c8] = *(const uint4*)&tile[row * 512 + c8];
        }
    } else {
        int nsb = (N + NPB - 1) / NPB;
        int blk = bx - nb_hrel;
        // local exclusive scan of RAW binTot
        int v = (t < nsb) ? binTot[t] : 0;
        sd[t] = v;
        __syncthreads();
        for (int off = 1; off < 256; off <<= 1) {
            int x = (t >= off) ? sd[t - off] : 0;
            __syncthreads();
            sd[t] += x;
            __syncthreads();
        }
        if (t < nsb) cur[t] = histT[t * NPLACE + blk] + sd[t] - v;
        __syncthreads();
        int bpb = (E + NPLACE - 1) / NPLACE;
        int e0 = blk * bpb;
        int e1 = e0 + bpb; if (e1 > E) e1 = E;
        for (int e = e0 + t; e < e1; e += 256) {
            int d = dst[e];
            int pos = atomicAdd(&cur[d >> 9], 1);
            tmp[pos] = src[e] | (et[e] << 17) | ((d & 511) << 21);
        }
    }
}

// ---------------------------------------------------------------------------
// k_sortbin: one 1024-thread block per super-bin. Local scan of raw binTot
// -> [start,end); counts per-node degrees in LDS, scans -> rowptr + scale_s
// partial, then places records in exact per-node order.
// ---------------------------------------------------------------------------
__global__ __launch_bounds__(1024) void k_sortbin(
        const int* __restrict__ tmp, int* __restrict__ packed,
        const int* __restrict__ binTot,
        int* __restrict__ rowptr, float* __restrict__ scale_s,
        int N, int E, int nsb) {
    __shared__ int cnt[NPB];
    __shared__ int sd[NPB];
    __shared__ float sf[1024];
    __shared__ int sstart, send;
    int t = threadIdx.x;
    int bin = blockIdx.x;
    int n0 = bin * NPB;
    if (t < NPB) cnt[t] = 0;
    // --- local scan of raw binTot -> [start,end) ---
    if (t < 256) sd[t] = (t < nsb) ? binTot[t] : 0;
    __syncthreads();
    for (int off = 1; off < 256; off <<= 1) {
        int x = (t < 256 && t >= off) ? sd[t - off] : 0;
        __syncthreads();
        if (t < 256) sd[t] += x;
        __syncthreads();
    }
    if (t == 0) {
        send = sd[bin];
        sstart = (bin == 0) ? 0 : sd[bin - 1];
    }
    __syncthreads();
    int start = sstart, end = send;
    // --- pass 1: per-node counts ---
    for (int i = start + t; i < end; i += 1024)
        atomicAdd(&cnt[(tmp[i] >> 21) & 511], 1);
    __syncthreads();
    // --- scan the 512 counts (inclusive into sd) ---
    if (t < NPB) sd[t] = cnt[t];
    __syncthreads();
    for (int off = 1; off < NPB; off <<= 1) {
        int x = (t < NPB && t >= off) ? sd[t - off] : 0;
        __syncthreads();
        if (t < NPB) sd[t] += x;
        __syncthreads();
    }
    float f = 0.f;
    if (t < NPB) {
        int node = n0 + t;
        int excl = sd[t] - cnt[t];
        if (node <= N) rowptr[node] = start + excl;
        if (node < N) f = logf((float)cnt[t] + 1.f);
    }
    if (t == 0 && bin == nsb - 1 && (N % NPB) == 0) rowptr[N] = end;
    sf[t] = f;
    __syncthreads();
    for (int s2 = 512; s2 > 0; s2 >>= 1) {
        if (t < s2) sf[t] += sf[t + s2];
        __syncthreads();
    }
    if (t == 0) atomicAdd(scale_s, sf[0]);
    // --- seed cursors ---
    if (t < NPB) cnt[t] = start + sd[t] - cnt[t];
    __syncthreads();
    // --- pass 2: place ---
    for (int i = start + t; i < end; i += 1024) {
        int rec = tmp[i];
        int pos = atomicAdd(&cnt[(rec >> 21) & 511], 1);
        packed[pos] = rec;
    }
}

// ---------------------------------------------------------------------------
// k_node_agg: one node per 64-lane wave, QUARTER decomposition: lane =
// (quarter q, lq, cols c2=2*lq). One gather instruction covers 4 edges'
// rows (each 16-lane quarter reads a 64B row as half2/lane). 16-lane DPP
// row-reduce (4 steps) + 1 bpermute broadcast + 1 sigmoid per 4 edges.
// Cross-quarter combine via 2 shfl_xor at the end. Fused epilogue.
// ---------------------------------------------------------------------------
__global__ __launch_bounds__(256) void k_node_agg(
        const __half* __restrict__ hrel16, const __half* __restrict__ hA1,
        const float* __restrict__ hA2, const float* __restrict__ relA,
        const float* __restrict__ B_w, const float* __restrict__ B_b,
        const float* __restrict__ curr, const float* __restrict__ bias,
        const int* __restrict__ rowptr,
        const int* __restrict__ packed, const float* __restrict__ scale_s,
        float* __restrict__ out, int N) {
    int t = threadIdx.x;
    int wave = t >> 6, t64 = t & 63;
    int q = t64 >> 4;                 // quarter 0..3
    int lq = t64 & 15;                // lane in quarter
    int c2 = lq * 2;                  // column pair base
    int n = blockIdx.x * 4 + wave;
    if (n >= N) return;
    int r0 = rowptr[n], r1 = rowptr[n + 1];
    float2 hA2n = *(const float2*)&hA2[n * 32 + c2];
    float2 bw2  = *(const float2*)&B_w[c2];
    float bb = B_b[0];
    float acc0 = 0.f, acc1 = 0.f;
    for (int c0 = r0; c0 < r1; c0 += 64) {
        int j = c0 + t64;
        int pk = (j < r1) ? packed[j] : 0;
        int m = r1 - c0; if (m > 64) m = 64;
        for (int k = 0; k < m; k += 4) {
            int idx = k + q;                       // this quarter's edge
            int pkq = __shfl(pk, idx, 64);
            int s = pkq & 0x1FFFF, r = (pkq >> 17) & 15;
            __half2 msg2 = *(const __half2*)&hrel16[(size_t)s * 512 + (r << 5) + c2];
            __half2 a12  = *(const __half2*)&hA1[(s << 5) + c2];
            float2 ra2 = *(const float2*)&relA[(r << 5) + c2];
            float z0 = __half2float(a12.x) + hA2n.x + ra2.x;
            float z1 = __half2float(a12.y) + hA2n.y + ra2.y;
            float p = fmaxf(z0, 0.f) * bw2.x + fmaxf(z1, 0.f) * bw2.y;
            // 16-lane row reduce on VALU pipe (lane15 of each row = sum)
            p = dpp_add_f<0x111>(p);
            p = dpp_add_f<0x112>(p);
            p = dpp_add_f<0x114>(p);
            p = dpp_add_f<0x118>(p);
            float ps = __shfl(p, (t64 & 48) | 15, 64) + bb;
            float a = 1.f / (1.f + __expf(-ps));
            if (idx < m) {
                acc0 += a * __half2float(msg2.x);
                acc1 += a * __half2float(msg2.y);
            }
        }
    }
    // combine the four quarters (each holds the same column pair c2)
    acc0 += __shfl_xor(acc0, 16, 64); acc1 += __shfl_xor(acc1, 16, 64);
    acc0 += __shfl_xor(acc0, 32, 64); acc1 += __shfl_xor(acc1, 32, 64);
    if (q == 0) {
        float deg = (float)(r1 - r0);
        float smean = scale_s[0] / (float)N;
        float sc = (logf(deg + 1.0f) / smean) / fmaxf(deg, 1.f);
        float2 cv = *(const float2*)&curr[n * 32 + c2];
        float2 o2;
        o2.x = fmaxf(cv.x + sc * acc0 + bias[c2], 0.f);
        o2.y = fmaxf(cv.y + sc * acc1 + bias[c2 + 1], 0.f);
        *(float2*)&out[n * 32 + c2] = o2;
    }
}

extern "C" void kernel_launch(void* const* d_in, const int* in_sizes, int n_in,
                              void* d_out, int out_size, void* d_ws, size_t ws_size,
                              hipStream_t stream) {
    const float* h        = (const float*)d_in[0];
    const float* weight   = (const float*)d_in[1];
    const float* w_comp   = (const float*)d_in[2];
    const float* slw      = (const float*)d_in[3];
    const float* bias     = (const float*)d_in[4];
    const float* attn_emb = (const float*)d_in[5];
    const float* A_w      = (const float*)d_in[6];
    const float* A_b      = (const float*)d_in[7];
    const float* B_w      = (const float*)d_in[8];
    const float* B_b      = (const float*)d_in[9];
    const int*   src      = (const int*)d_in[10];
    const int*   dst      = (const int*)d_in[11];
    const int*   et       = (const int*)d_in[12];
    float*       out      = (float*)d_out;

    int N = in_sizes[0] / 32;
    int E = in_sizes[10];
    int nsb = (N + NPB - 1) / NPB;

    char* ws = (char*)d_ws;
    size_t off = 0;
    auto alloc = [&](size_t nbytes) {
        char* p = ws + off;
        off += (nbytes + 63) & ~((size_t)63);
        return p;
    };
    float*     scale_s = (float*)    alloc(4);
    size_t zero_bytes = off;                       // scale_s only
    int*       rowptr  = (int*)      alloc((size_t)(N + 1) * 4);
    int*       histT   = (int*)      alloc((size_t)nsb * NPLACE * 4);
    int*       binTot  = (int*)      alloc((size_t)(nsb + 1) * 4);
    _Float16*  relwB16 = (_Float16*) alloc((size_t)NREL * 1024 * 2);
    float*     relA    = (float*)    alloc((size_t)NREL * 32 * 4);
    __half*    hA1     = (__half*)   alloc((size_t)N * 32 * 2);
    _Float16*  h16     = (_Float16*) alloc((size_t)N * 32 * 2);
    float*     hA2     = (float*)    alloc((size_t)N * 32 * 4);
    float*     curr    = (float*)    alloc((size_t)N * 32 * 4);
    int*       tmp     = (int*)      alloc((size_t)E * 4);
    int*       packed  = (int*)      alloc((size_t)E * 4);
    __half*    hrel16  = (__half*)   alloc((size_t)N * 512 * 2);
    size_t need = off;

    if (ws_size < need) {
        fprintf(stderr, "kernel_launch: ws too small (%zu < %zu bytes) — no work launched\n",
                ws_size, need);
        return;
    }

    (void)hipMemsetAsync(d_ws, 0, zero_bytes, stream);

    int nb_pre = (N + 63) / 64;
    k_fused1<<<nb_pre + NPLACE, 256, 0, stream>>>(
        h, A_w, slw, dst, hA1, h16, hA2, curr, histT, N, E, nb_pre);

    k_scanH_prep<<<nsb + 64, NPLACE, 0, stream>>>(
        histT, binTot, weight, w_comp, attn_emb, A_w, A_b, relwB16, relA, nsb);

    int nb_hrel = (N + 15) / 16;
    k_fused2<<<nb_hrel + NPLACE, 256, 0, stream>>>(
        h16, relwB16, hrel16, src, dst, et, histT, binTot, tmp, N, E, nb_hrel);

    k_sortbin<<<nsb, 1024, 0, stream>>>(tmp, packed, binTot, rowptr, scale_s, N, E, nsb);

    k_node_agg<<<(N + 3) / 4, 256, 0, stream>>>(
        hrel16, hA1, hA2, relA, B_w, B_b, curr, bias,
        rowptr, packed, scale_s, out, N);
}

// Round 16
// 147.895 us; speedup vs baseline: 1.0864x; 1.0864x over previous
//
#include <hip/hip_runtime.h>
#include <hip/hip_fp16.h>
#include <cstdio>
#include <cstdint>

#define NREL 16
#define NBASE 8
#define NPB 512            // nodes per super-bin (bin = dst >> 9)
#define NPLACE 256         // histogram/place blocks
// Record packing: src[16:0] | et[20:17] | dlow[29:21]  (N <= 2^17)

typedef _Float16 half8 __attribute__((ext_vector_type(8)));
typedef float floatx4 __attribute__((ext_vector_type(4)));

// ---------------------------------------------------------------------------
template <int CTRL>
__device__ __forceinline__ float dpp_add_f(float x) {
    int xi = __builtin_bit_cast(int, x);
    int yi = __builtin_amdgcn_update_dpp(0, xi, CTRL, 0xF, 0xF, true);
    return x + __builtin_bit_cast(float, yi);
}

// ---------------------------------------------------------------------------
// k_fused1: two independent jobs, selected by block range:
//   [0, nb_pre)          node_pre via MFMA (64 nodes/block, 16/wave):
//                        hA1 (fp16), hA2 (f32), curr (f32), h16 (A-frag cvt)
//   [nb_pre, +NPLACE)    hist2: per-(block,super-bin) LDS histogram of dst;
//                        block 0 also zero-initializes scale_s (consumed only
//                        by k_sortbin, 3 launches later — ordering safe).
// ---------------------------------------------------------------------------
__global__ __launch_bounds__(256) void k_fused1(
        const float* __restrict__ h, const float* __restrict__ A_w,
        const float* __restrict__ slw,
        const int* __restrict__ dst,
        __half* __restrict__ hA1, _Float16* __restrict__ h16,
        float* __restrict__ hA2, float* __restrict__ curr,
        int* __restrict__ histT, float* __restrict__ scale_s,
        int N, int E, int nb_pre) {
    __shared__ int hist[256];
    int bx = blockIdx.x;
    int t = threadIdx.x;
    if (bx < nb_pre) {
        // ---- node_pre via MFMA ----
        int w = t >> 6, l = t & 63;
        int n0 = bx * 64 + w * 16;
        if (n0 >= N) return;
        int lr = l & 15, lg = l >> 4;
        int anode = n0 + lr;
        int arc = (anode < N) ? anode : N - 1;   // clamp; stores masked
        int ac = lg * 8;
        float4 hv0 = *(const float4*)&h[(size_t)arc * 32 + ac];
        float4 hv1 = *(const float4*)&h[(size_t)arc * 32 + ac + 4];
        half8 af;
        af[0] = (_Float16)hv0.x; af[1] = (_Float16)hv0.y;
        af[2] = (_Float16)hv0.z; af[3] = (_Float16)hv0.w;
        af[4] = (_Float16)hv1.x; af[5] = (_Float16)hv1.y;
        af[6] = (_Float16)hv1.z; af[7] = (_Float16)hv1.w;
        if (anode < N)
            *(uint4*)&h16[(size_t)anode * 32 + ac] = *(const uint4*)&af;
        #pragma unroll
        for (int g = 0; g < 6; ++g) {
            half8 bf;
            #pragma unroll
            for (int j = 0; j < 8; ++j) {
                int i = lg * 8 + j;                  // k index (h feature)
                int oc = g * 16 + lr;                // out col 0..95
                float v;
                if (g < 2)      v = A_w[i * 32 + oc];
                else if (g < 4) v = A_w[(32 + i) * 32 + (oc - 32)];
                else            v = slw[i * 32 + (oc - 64)];
                bf[j] = (_Float16)v;
            }
            floatx4 d = {0.f, 0.f, 0.f, 0.f};
            d = __builtin_amdgcn_mfma_f32_16x16x32_f16(af, bf, d, 0, 0, 0);
            #pragma unroll
            for (int q = 0; q < 4; ++q) {
                int node = n0 + lg * 4 + q;          // D row = node
                int oc = g * 16 + lr;                // D col = out col
                if (node < N) {
                    if (g < 2)      hA1[(size_t)node * 32 + oc] = __float2half(d[q]);
                    else if (g < 4) hA2[(size_t)node * 32 + (oc - 32)] = d[q];
                    else            curr[(size_t)node * 32 + (oc - 64)] = d[q];
                }
            }
        }
    } else {
        // ---- hist2 ----
        int nsb = (N + NPB - 1) / NPB;
        int blk = bx - nb_pre;
        if (blk == 0 && t == 0) scale_s[0] = 0.f;    // replaces hipMemsetAsync
        hist[t] = 0;
        __syncthreads();
        int bpb = (E + NPLACE - 1) / NPLACE;
        int e0 = blk * bpb;
        int e1 = e0 + bpb; if (e1 > E) e1 = E;
        for (int e = e0 + t; e < e1; e += 256)
            atomicAdd(&hist[dst[e] >> 9], 1);
        __syncthreads();
        if (t < nsb) histT[t * NPLACE + blk] = hist[t];
    }
}

// ---------------------------------------------------------------------------
// k_scanH_prep: two jobs by block range:
//   [0, nsb)      per-super-bin exclusive scan of NPLACE block-counts
//                 (in place, bin-LOCAL); bin RAW total -> binTot[bin].
//   [nsb, +64)    prep: relwB16 (MFMA B-frag layout) + relA.
// ---------------------------------------------------------------------------
__global__ __launch_bounds__(NPLACE) void k_scanH_prep(
        int* __restrict__ histT, int* __restrict__ binTot,
        const float* __restrict__ weight, const float* __restrict__ w_comp,
        const float* __restrict__ attn_emb, const float* __restrict__ A_w,
        const float* __restrict__ A_b,
        _Float16* __restrict__ relwB16, float* __restrict__ relA, int nsb) {
    __shared__ int sd[NPLACE];
    int bx = blockIdx.x, t = threadIdx.x;
    if (bx < nsb) {
        int bin = bx;
        int v = histT[bin * NPLACE + t];
        sd[t] = v;
        __syncthreads();
        for (int off = 1; off < NPLACE; off <<= 1) {
            int x = (t >= off) ? sd[t - off] : 0;
            __syncthreads();
            sd[t] += x;
            __syncthreads();
        }
        histT[bin * NPLACE + t] = sd[t] - v;
        if (t == NPLACE - 1) binTot[bin] = sd[NPLACE - 1];
    } else {
        int pidx = (bx - nsb) * 256 + t;             // 0..16383
        int r = pidx >> 10, rem = pidx & 1023;
        int nb = rem >> 9, lj = rem & 511;
        int l = lj >> 3, j = lj & 7;
        int i = ((l >> 4) << 3) + j;                 // k index
        int o = nb * 16 + (l & 15);                  // n index
        float acc = 0.f;
        #pragma unroll
        for (int b = 0; b < NBASE; ++b)
            acc += w_comp[r * NBASE + b] * weight[b * 1024 + i * 32 + o];
        relwB16[pidx] = (_Float16)acc;
        if (pidx < 512) {
            int rr = pidx >> 5, oo = pidx & 31;
            float a = A_b[oo];
            #pragma unroll 8
            for (int ii = 0; ii < 32; ++ii)
                a += attn_emb[rr * 32 + ii] * A_w[(64 + ii) * 32 + oo];
            relA[pidx] = a;
        }
    }
}

// ---------------------------------------------------------------------------
// k_fused2: two independent jobs by block range:
//   [0, nb_hrel)          hrel via MFMA: 16-node tile, wave w covers
//                         col-groups w*8..w*8+7; D staged in LDS, written
//                         coalesced as uint4.
//   [nb_hrel, +NPLACE)    place: local scan of raw binTot -> absolute bases;
//                         LDS cursors, contiguous runs, LDS atomics only.
// ---------------------------------------------------------------------------
__global__ __launch_bounds__(256) void k_fused2(
        const _Float16* __restrict__ h16, const _Float16* __restrict__ relwB16,
        __half* __restrict__ hrel16,
        const int* __restrict__ src, const int* __restrict__ dst,
        const int* __restrict__ et,
        const int* __restrict__ histT, const int* __restrict__ binTot,
        int* __restrict__ tmp,
        int N, int E, int nb_hrel) {
    __shared__ __align__(16) _Float16 tile[16 * 512];   // 16KB
    __shared__ int cur[256];
    __shared__ int sd[256];
    int bx = blockIdx.x;
    int t = threadIdx.x;
    if (bx < nb_hrel) {
        int n0 = bx * 16;
        int l = t & 63, w = t >> 6;
        int ar = n0 + (l & 15);
        if (ar >= N) ar = N - 1;
        half8 af = *(const half8*)(h16 + (size_t)ar * 32 + ((l >> 4) << 3));
        #pragma unroll
        for (int gg = 0; gg < 8; ++gg) {
            int g = w * 8 + gg;
            half8 bf = *(const half8*)(relwB16 + (size_t)g * 512 + l * 8);
            floatx4 d = {0.f, 0.f, 0.f, 0.f};
            d = __builtin_amdgcn_mfma_f32_16x16x32_f16(af, bf, d, 0, 0, 0);
            #pragma unroll
            for (int q = 0; q < 4; ++q) {
                int row = ((l >> 4) << 2) + q;
                tile[row * 512 + g * 16 + (l & 15)] = (_Float16)d[q];
            }
        }
        __syncthreads();
        #pragma unroll
        for (int p = 0; p < 4; ++p) {
            int idx = p * 256 + t;
            int row = idx >> 6, c8 = (idx & 63) << 3;
            int n = n0 + row;
            if (n < N)
                *(uint4*)&hrel16[(size_t)n * 512 + c8] = *(const uint4*)&tile[row * 512 + c8];
        }
    } else {
        int nsb = (N + NPB - 1) / NPB;
        int blk = bx - nb_hrel;
        // local exclusive scan of RAW binTot
        int v = (t < nsb) ? binTot[t] : 0;
        sd[t] = v;
        __syncthreads();
        for (int off = 1; off < 256; off <<= 1) {
            int x = (t >= off) ? sd[t - off] : 0;
            __syncthreads();
            sd[t] += x;
            __syncthreads();
        }
        if (t < nsb) cur[t] = histT[t * NPLACE + blk] + sd[t] - v;
        __syncthreads();
        int bpb = (E + NPLACE - 1) / NPLACE;
        int e0 = blk * bpb;
        int e1 = e0 + bpb; if (e1 > E) e1 = E;
        for (int e = e0 + t; e < e1; e += 256) {
            int d = dst[e];
            int pos = atomicAdd(&cur[d >> 9], 1);
            tmp[pos] = src[e] | (et[e] << 17) | ((d & 511) << 21);
        }
    }
}

// ---------------------------------------------------------------------------
// k_sortbin: one 1024-thread block per super-bin. Local scan of raw binTot
// -> [start,end); counts per-node degrees in LDS, scans -> rowptr + scale_s
// partial, then places records in exact per-node order.
// ---------------------------------------------------------------------------
__global__ __launch_bounds__(1024) void k_sortbin(
        const int* __restrict__ tmp, int* __restrict__ packed,
        const int* __restrict__ binTot,
        int* __restrict__ rowptr, float* __restrict__ scale_s,
        int N, int E, int nsb) {
    __shared__ int cnt[NPB];
    __shared__ int sd[NPB];
    __shared__ float sf[1024];
    __shared__ int sstart, send;
    int t = threadIdx.x;
    int bin = blockIdx.x;
    int n0 = bin * NPB;
    if (t < NPB) cnt[t] = 0;
    // --- local scan of raw binTot -> [start,end) ---
    if (t < 256) sd[t] = (t < nsb) ? binTot[t] : 0;
    __syncthreads();
    for (int off = 1; off < 256; off <<= 1) {
        int x = (t < 256 && t >= off) ? sd[t - off] : 0;
        __syncthreads();
        if (t < 256) sd[t] += x;
        __syncthreads();
    }
    if (t == 0) {
        send = sd[bin];
        sstart = (bin == 0) ? 0 : sd[bin - 1];
    }
    __syncthreads();
    int start = sstart, end = send;
    // --- pass 1: per-node counts ---
    for (int i = start + t; i < end; i += 1024)
        atomicAdd(&cnt[(tmp[i] >> 21) & 511], 1);
    __syncthreads();
    // --- scan the 512 counts (inclusive into sd) ---
    if (t < NPB) sd[t] = cnt[t];
    __syncthreads();
    for (int off = 1; off < NPB; off <<= 1) {
        int x = (t < NPB && t >= off) ? sd[t - off] : 0;
        __syncthreads();
        if (t < NPB) sd[t] += x;
        __syncthreads();
    }
    float f = 0.f;
    if (t < NPB) {
        int node = n0 + t;
        int excl = sd[t] - cnt[t];
        if (node <= N) rowptr[node] = start + excl;
        if (node < N) f = logf((float)cnt[t] + 1.f);
    }
    if (t == 0 && bin == nsb - 1 && (N % NPB) == 0) rowptr[N] = end;
    sf[t] = f;
    __syncthreads();
    for (int s2 = 512; s2 > 0; s2 >>= 1) {
        if (t < s2) sf[t] += sf[t + s2];
        __syncthreads();
    }
    if (t == 0) atomicAdd(scale_s, sf[0]);
    // --- seed cursors ---
    if (t < NPB) cnt[t] = start + sd[t] - cnt[t];
    __syncthreads();
    // --- pass 2: place ---
    for (int i = start + t; i < end; i += 1024) {
        int rec = tmp[i];
        int pos = atomicAdd(&cnt[(rec >> 21) & 511], 1);
        packed[pos] = rec;
    }
}

// ---------------------------------------------------------------------------
// k_node_agg (R14-verified optimum): one node per 64-lane wave, 2 edges per
// step (one per 32-half), 2 steps batched (4 edges' gathers in flight).
// CSR gather from fp16 tables, DPP attention reduce, register accumulate,
// fused epilogue.
// ---------------------------------------------------------------------------
__global__ __launch_bounds__(256) void k_node_agg(
        const __half* __restrict__ hrel16, const __half* __restrict__ hA1,
        const float* __restrict__ hA2, const float* __restrict__ relA,
        const float* __restrict__ B_w, const float* __restrict__ B_b,
        const float* __restrict__ curr, const float* __restrict__ bias,
        const int* __restrict__ rowptr,
        const int* __restrict__ packed, const float* __restrict__ scale_s,
        float* __restrict__ out, int N) {
    int t = threadIdx.x;
    int wave = t >> 6, t64 = t & 63;
    int half = t64 >> 5, o = t64 & 31;
    int n = blockIdx.x * 4 + wave;
    if (n >= N) return;
    int r0 = rowptr[n], r1 = rowptr[n + 1];
    float hA2n = hA2[n * 32 + o];
    float bwo = B_w[o];
    float bb  = B_b[0];
    float acc = 0.f;
    for (int c0 = r0; c0 < r1; c0 += 64) {
        int j = c0 + t64;
        int pk = (j < r1) ? packed[j] : 0;
        int m = r1 - c0; if (m > 64) m = 64;
        for (int k = 0; k < m; k += 4) {
            int idxA = k + half;
            int idxB = k + 2 + half;
            int pkA = __shfl(pk, idxA, 64);
            int pkB = __shfl(pk, idxB, 64);
            int sA = pkA & 0x1FFFF, rA = (pkA >> 17) & 15;
            int sB = pkB & 0x1FFFF, rB = (pkB >> 17) & 15;
            float msgA = __half2float(hrel16[(size_t)sA * 512 + (rA << 5) + o]);
            float a1A  = __half2float(hA1[(sA << 5) + o]);
            float msgB = __half2float(hrel16[(size_t)sB * 512 + (rB << 5) + o]);
            float a1B  = __half2float(hA1[(sB << 5) + o]);
            float zA = a1A + hA2n + relA[(rA << 5) + o];
            float zB = a1B + hA2n + relA[(rB << 5) + o];
            float pA = fmaxf(zA, 0.f) * bwo;
            float pB = fmaxf(zB, 0.f) * bwo;
            pA = dpp_add_f<0x111>(pA); pB = dpp_add_f<0x111>(pB);
            pA = dpp_add_f<0x112>(pA); pB = dpp_add_f<0x112>(pB);
            pA = dpp_add_f<0x114>(pA); pB = dpp_add_f<0x114>(pB);
            pA = dpp_add_f<0x118>(pA); pB = dpp_add_f<0x118>(pB);
            pA = dpp_add_f<0x142>(pA); pB = dpp_add_f<0x142>(pB);
            pA = __shfl(pA, 31, 32) + bb;
            pB = __shfl(pB, 31, 32) + bb;
            float aA = 1.f / (1.f + __expf(-pA));
            float aB = 1.f / (1.f + __expf(-pB));
            acc += (idxA < m) ? aA * msgA : 0.f;
            acc += (idxB < m) ? aB * msgB : 0.f;
        }
    }
    acc += __shfl_xor(acc, 32, 64);
    if (half == 0) {
        float deg = (float)(r1 - r0);
        float smean = scale_s[0] / (float)N;
        float scale = logf(deg + 1.0f);
        float v = curr[n * 32 + o] + (scale / smean) * acc / fmaxf(deg, 1.f) + bias[o];
        out[n * 32 + o] = fmaxf(v, 0.f);
    }
}

extern "C" void kernel_launch(void* const* d_in, const int* in_sizes, int n_in,
                              void* d_out, int out_size, void* d_ws, size_t ws_size,
                              hipStream_t stream) {
    const float* h        = (const float*)d_in[0];
    const float* weight   = (const float*)d_in[1];
    const float* w_comp   = (const float*)d_in[2];
    const float* slw      = (const float*)d_in[3];
    const float* bias     = (const float*)d_in[4];
    const float* attn_emb = (const float*)d_in[5];
    const float* A_w      = (const float*)d_in[6];
    const float* A_b      = (const float*)d_in[7];
    const float* B_w      = (const float*)d_in[8];
    const float* B_b      = (const float*)d_in[9];
    const int*   src      = (const int*)d_in[10];
    const int*   dst      = (const int*)d_in[11];
    const int*   et       = (const int*)d_in[12];
    float*       out      = (float*)d_out;

    int N = in_sizes[0] / 32;
    int E = in_sizes[10];
    int nsb = (N + NPB - 1) / NPB;

    char* ws = (char*)d_ws;
    size_t off = 0;
    auto alloc = [&](size_t nbytes) {
        char* p = ws + off;
        off += (nbytes + 63) & ~((size_t)63);
        return p;
    };
    float*     scale_s = (float*)    alloc(4);
    int*       rowptr  = (int*)      alloc((size_t)(N + 1) * 4);
    int*       histT   = (int*)      alloc((size_t)nsb * NPLACE * 4);
    int*       binTot  = (int*)      alloc((size_t)(nsb + 1) * 4);
    _Float16*  relwB16 = (_Float16*) alloc((size_t)NREL * 1024 * 2);
    float*     relA    = (float*)    alloc((size_t)NREL * 32 * 4);
    __half*    hA1     = (__half*)   alloc((size_t)N * 32 * 2);
    _Float16*  h16     = (_Float16*) alloc((size_t)N * 32 * 2);
    float*     hA2     = (float*)    alloc((size_t)N * 32 * 4);
    float*     curr    = (float*)    alloc((size_t)N * 32 * 4);
    int*       tmp     = (int*)      alloc((size_t)E * 4);
    int*       packed  = (int*)      alloc((size_t)E * 4);
    __half*    hrel16  = (__half*)   alloc((size_t)N * 512 * 2);
    size_t need = off;

    if (ws_size < need) {
        fprintf(stderr, "kernel_launch: ws too small (%zu < %zu bytes) — no work launched\n",
                ws_size, need);
        return;
    }

    int nb_pre = (N + 63) / 64;
    k_fused1<<<nb_pre + NPLACE, 256, 0, stream>>>(
        h, A_w, slw, dst, hA1, h16, hA2, curr, histT, scale_s, N, E, nb_pre);

    k_scanH_prep<<<nsb + 64, NPLACE, 0, stream>>>(
        histT, binTot, weight, w_comp, attn_emb, A_w, A_b, relwB16, relA, nsb);

    int nb_hrel = (N + 15) / 16;
    k_fused2<<<nb_hrel + NPLACE, 256, 0, stream>>>(
        h16, relwB16, hrel16, src, dst, et, histT, binTot, tmp, N, E, nb_hrel);

    k_sortbin<<<nsb, 1024, 0, stream>>>(tmp, packed, binTot, rowptr, scale_s, N, E, nsb);

    k_node_agg<<<(N + 3) / 4, 256, 0, stream>>>(
        hrel16, hA1, hA2, relA, B_w, B_b, curr, bias,
        rowptr, packed, scale_s, out, N);
}